// Round 7
// baseline (384.696 us; speedup 1.0000x reference)
//
#include <hip/hip_runtime.h>
#include <stdint.h>

// SO3Conv mapped per l to GEMM: C[(b,m),(g,v)] = A[(b,m),(u,f)] * B[(u,f),(g,v)]
//   A: pre-transposed x, bf16, row-major [M=1024d][K=64d], k = u*64+f
//   B: psi with both norms folded, bf16, B-operand layout Bt[n=(g*d+v)][k], rows padded to 128-mult with 0
// Workspace: A buffers then B buffers, ~63.8 MB.
// R1: double-buffer + XOR swizzle (bank conflicts 5.3M -> 0, dur flat).
// R3/R5: counted-vmcnt 3-buffer pipeline: both 116.5us, MfmaUtil 15%.
// R6: 256x128 tile, wave-tile 128x64: 107.9us, MfmaUtil 16%. No pipe saturated; GEMM is in the
//     skinny-shape latency regime (405 TF > m102's N~1024 reference) -> gemm frozen.
// R7: attack the invisible ~236us constant (prep + harness): prep transpose was SCALAR 4B
//     global loads (Common-mistake #2). Vectorize: 16B dwordx4 loads (align-4 vector type,
//     stride-169 smem rows ~2-way conflicts), 8B uint2 packed A-stores. Same layout bit-for-bit.

typedef __bf16 bf16x8 __attribute__((ext_vector_type(8)));
typedef float floatx4 __attribute__((ext_vector_type(4)));
typedef float f4u __attribute__((ext_vector_type(4), aligned(4)));   // unaligned-capable float4

#define XROW 29120   // 64*455

__device__ __forceinline__ unsigned short f2bf(float f) {
  union { float f; unsigned int u; } c; c.f = f;
  unsigned int u = c.u;
  return (unsigned short)((u + 0x7FFFu + ((u >> 16) & 1u)) >> 16);
}
__device__ __forceinline__ unsigned int pack2(float a, float b) {
  return (unsigned int)f2bf(a) | ((unsigned int)f2bf(b) << 16);
}

__host__ __device__ constexpr int d_of(int L) { return 2 * L + 1; }
__host__ __device__ constexpr int off_of(int L) { int s = 0; for (int i = 0; i < L; ++i) s += d_of(i) * d_of(i); return s; }
__host__ __device__ constexpr size_t a_off(int L) { size_t s = 0; for (int i = 0; i < L; ++i) s += (size_t)65536 * d_of(i) * d_of(i); return s; }
__host__ __device__ constexpr size_t b_off(int L) { size_t s = a_off(7); for (int i = 0; i < L; ++i) s += (size_t)4096 * d_of(i) * (d_of(i) + 1); return s; }

// ---------------- Kernel 1 (fused): build B (blocks 0..447) + transpose x (blocks 448..1471) ----------------
__global__ __launch_bounds__(256) void prep(const float* __restrict__ x, const float* __restrict__ Dm,
                                            const float* __restrict__ w, unsigned short* __restrict__ ws) {
  __shared__ __align__(16) float smem[64 * 68 + 64 * 172];   // 60 KB: build uses both halves; transpose uses 64x169
  const int tid = threadIdx.x;
  const int bid = blockIdx.x;

  if (bid < 448) {
    // ---- build B: psi[f,g,r] = sum_n w[f,g,n] D[n,off+r], norms folded, 4x4 register tiling ----
    float* wg = smem;              // [64][68]: wg[n][f]
    float* Dl = smem + 64 * 68;    // [64][172]: Dl[n][r], zero-padded to r<172
    const int g = bid & 63, l = bid >> 6;
    const int d = 2 * l + 1, d2 = d * d, K = 64 * d;
    int off = 0; size_t boff = a_off(7);
    for (int i = 0; i < l; ++i) { int dd = 2 * i + 1; off += dd * dd; boff += (size_t)4096 * dd * (dd + 1); }
    unsigned short* B = ws + boff;

    for (int t = tid; t < 4096; t += 256) {
      int n = t & 63, f = t >> 6;
      wg[n * 68 + f] = w[(size_t)f * 4096 + g * 64 + n];
    }
    for (int t = tid; t < 64 * 172; t += 256) {
      int n = t / 172, r = t - n * 172;
      Dl[t] = (r < d2) ? Dm[n * 455 + off + r] : 0.f;
    }
    __syncthreads();

    const float sl = 1.0f / (64.0f * sqrtf((float)d));
    const int RT = (d2 + 3) >> 2;
    for (int tt = tid; tt < 16 * RT; tt += 256) {
      const int ft = tt & 15, rt = tt >> 4;
      float acc[4][4] = {};
      for (int n = 0; n < 64; ++n) {
        floatx4 wv = *(const floatx4*)(wg + n * 68 + ft * 4);
        floatx4 dv = *(const floatx4*)(Dl + n * 172 + rt * 4);
#pragma unroll
        for (int a = 0; a < 4; ++a)
#pragma unroll
          for (int b2 = 0; b2 < 4; ++b2) acc[a][b2] += wv[a] * dv[b2];
      }
#pragma unroll
      for (int b2 = 0; b2 < 4; ++b2) {
        int r = rt * 4 + b2;
        if (r < d2) {
          int u = r / d, v = r - u * d;
          size_t base = (size_t)(g * d + v) * K + u * 64 + ft * 4;
#pragma unroll
          for (int a = 0; a < 4; ++a) B[base + a] = f2bf(acc[a][b2] * sl);
        }
      }
    }
    { // zero one pad row per g (rows 64d..64d+63 across the 64 g-blocks)
      int nn = 64 * d + g;
      for (int k = tid; k < K; k += 256) B[(size_t)nn * K + k] = 0;
    }
  } else {
    // ---- transpose x -> A (bf16): 16B vector loads, smem stride 169, 8B packed stores ----
    float* xs = smem;                       // [64][169]
    const int b = bid - 448;
    const float* xb = x + (size_t)b * XROW;
    size_t aoff = 0;

    // phase A: l0..l4 (cols 0..165), 4-col vector chunks (NC=42, tail=1)
    for (int t = tid; t < 64 * 42; t += 256) {
      int f = t / 42, ch = t - f * 42, c = ch * 4;
      const float* src = xb + (size_t)f * 455 + c;
      float* dst = xs + f * 169 + c;
      if (c + 4 <= 165) *(f4u*)dst = *(const f4u*)src;
      else dst[0] = src[0];
    }
    __syncthreads();
    int off = 0;
#pragma unroll
    for (int l = 0; l < 5; ++l) {
      const int d = 2 * l + 1, d2 = d * d, n1 = 64 * d2;
      uint2* A2 = (uint2*)(ws + aoff + (size_t)b * n1);
      for (int t = tid; t < (n1 >> 2); t += 256) {
        int f4i = t & 15, s = t >> 4;
        int u = s % d, m = s / d;
        const float* xc = xs + off + u * d + m;
        uint2 v2;
        v2.x = pack2(xc[(4 * f4i    ) * 169], xc[(4 * f4i + 1) * 169]);
        v2.y = pack2(xc[(4 * f4i + 2) * 169], xc[(4 * f4i + 3) * 169]);
        A2[t] = v2;
      }
      off += d2; aoff += (size_t)1024 * n1;
    }
    __syncthreads();
    // phase B: l5 (cols 165..286), NC=31 (tail=1)
    for (int t = tid; t < 64 * 31; t += 256) {
      int f = t / 31, ch = t - f * 31, c = ch * 4;
      const float* src = xb + (size_t)f * 455 + 165 + c;
      float* dst = xs + f * 169 + c;
      if (c + 4 <= 121) *(f4u*)dst = *(const f4u*)src;
      else dst[0] = src[0];
    }
    __syncthreads();
    {
      const int n1 = 64 * 121;
      uint2* A2 = (uint2*)(ws + aoff + (size_t)b * n1);
      for (int t = tid; t < (n1 >> 2); t += 256) {
        int f4i = t & 15, s = t >> 4;
        int u = s % 11, m = s / 11;
        const float* xc = xs + u * 11 + m;
        uint2 v2;
        v2.x = pack2(xc[(4 * f4i    ) * 169], xc[(4 * f4i + 1) * 169]);
        v2.y = pack2(xc[(4 * f4i + 2) * 169], xc[(4 * f4i + 3) * 169]);
        A2[t] = v2;
      }
      aoff += (size_t)1024 * n1;
    }
    __syncthreads();
    // phase C: l6 (cols 286..455), NC=43 (tail=1)
    for (int t = tid; t < 64 * 43; t += 256) {
      int f = t / 43, ch = t - f * 43, c = ch * 4;
      const float* src = xb + (size_t)f * 455 + 286 + c;
      float* dst = xs + f * 169 + c;
      if (c + 4 <= 169) *(f4u*)dst = *(const f4u*)src;
      else dst[0] = src[0];
    }
    __syncthreads();
    {
      const int n1 = 64 * 169;
      uint2* A2 = (uint2*)(ws + aoff + (size_t)b * n1);
      for (int t = tid; t < (n1 >> 2); t += 256) {
        int f4i = t & 15, s = t >> 4;
        int u = s % 13, m = s / 13;
        const float* xc = xs + u * 13 + m;
        uint2 v2;
        v2.x = pack2(xc[(4 * f4i    ) * 169], xc[(4 * f4i + 1) * 169]);
        v2.y = pack2(xc[(4 * f4i + 2) * 169], xc[(4 * f4i + 3) * 169]);
        A2[t] = v2;
      }
    }
  }
}

// ---------------- Kernel 2: fused all-l MFMA GEMM, 256x128 tile, wave-tile 128x64 (8x4 frags) ----------------
__device__ __forceinline__ void async_copy16(const void* gp, void* lp) {
  __builtin_amdgcn_global_load_lds((__attribute__((address_space(1))) void*)gp,
                                   (__attribute__((address_space(3))) void*)lp, 16, 0, 0);
}

template <int N>
__device__ __forceinline__ void wait_vmcnt() {
  asm volatile("s_waitcnt vmcnt(%0)" :: "n"(N) : "memory");
}

template <int L>
__device__ __forceinline__ void gemm_body(int local, const unsigned short* __restrict__ ws,
                                          float* __restrict__ out,
                                          unsigned short* As, unsigned short* Bs) {
  constexpr int d = 2 * L + 1;
  constexpr int K = 64 * d;
  constexpr int NT = (d + 1) / 2;          // N-tiles of 128 (N padded to 64*(d+1)); M-tiles of 256 = 4d
  constexpr int OFF = off_of(L);
  constexpr int KT = 2 * d;                // 32-wide k-steps
  const unsigned short* A = ws + a_off(L);
  const unsigned short* B = ws + b_off(L);
  // XCD-grouped dispatch: groups of 4 consecutive bids share the B-panel nt across 4 M-tiles.
  const int x4 = local & 3, tt = local >> 2;
  const int mt = (tt / NT) * 4 + x4;
  const int nt = tt % NT;
  const int tid = threadIdx.x;
  const int w = tid >> 6, ln = tid & 63;
  const int wm = w >> 1, wn = w & 1;       // wave-tile: rows wm*128..+128, cols wn*64..+64
  const int q = ln >> 4, r16 = ln & 15;

  // Staging: LDS dest linear (global_load_lds requirement); bank-conflict swizzle applied by
  // permuting the 16B k-chunk in the GLOBAL source address: chunk ^= (row>>1)&3.
  const unsigned short* gp[6];
  unsigned short* ldst[6];
#pragma unroll
  for (int i = 0; i < 6; ++i) {
    int c = i * 256 + tid;
    if (i < 4) {
      int row = c >> 2, ch = (c & 3) ^ ((c >> 3) & 3);
      gp[i] = A + (size_t)(mt * 256 + row) * K + ch * 8;
      ldst[i] = As + (i * 256 + w * 64) * 8;
    } else {
      int c2 = c - 1024;
      int row = c2 >> 2, ch = (c2 & 3) ^ ((c2 >> 3) & 3);
      gp[i] = B + (size_t)(nt * 128 + row) * K + ch * 8;
      ldst[i] = Bs + ((i - 4) * 256 + w * 64) * 8;
    }
  }

  // ds_read offsets with the matching XOR: stored chunk at slot (q^s) is global chunk q, s=(row>>1)&3
  const int sq = q ^ ((r16 >> 1) & 3);
  const int aoffs0 = (wm * 128 + r16) * 32 + sq * 8;   // af[mi] at +mi*512 (16 rows)
  const int boffs0 = (wn * 64 + r16) * 32 + sq * 8;    // bfr[ni] at +ni*512

  floatx4 acc[8][4] = {};

  // prologue: stage tiles 0,1 (6 global_load_lds each)
#pragma unroll
  for (int t = 0; t < 2; ++t) {
    if (t < KT) {
#pragma unroll
      for (int i = 0; i < 6; ++i) { async_copy16(gp[i], ldst[i] + t * (i < 4 ? 8192 : 4096)); gp[i] += 32; }
    }
  }

#pragma unroll
  for (int kt = 0; kt < KT; ++kt) {
    // Wait for tile kt: at most 1 younger tile (6 loads) in flight. Never 0 in steady state.
    if (kt < KT - 1) wait_vmcnt<6>();
    else             wait_vmcnt<0>();
    __builtin_amdgcn_s_barrier();            // tile kt resident for ALL waves
    __builtin_amdgcn_sched_barrier(0);       // nothing below may hoist above the rendezvous

    const unsigned short* Asc = As + (kt % 3) * 8192;
    const unsigned short* Bsc = Bs + (kt % 3) * 4096;
    bf16x8 af[8], bfr[4];
#pragma unroll
    for (int mi = 0; mi < 8; ++mi) af[mi] = *(const bf16x8*)(Asc + aoffs0 + mi * 512);
#pragma unroll
    for (int ni = 0; ni < 4; ++ni) bfr[ni] = *(const bf16x8*)(Bsc + boffs0 + ni * 512);

    if (kt + 2 < KT) {
      // buffer (kt+2)%3 == (kt-1)%3: safe — all waves past barrier kt have issued their kt-1 MFMAs,
      // whose compiler-inserted lgkmcnt waits retired the kt-1 ds_reads.
#pragma unroll
      for (int i = 0; i < 6; ++i) { async_copy16(gp[i], ldst[i] + ((kt + 2) % 3) * (i < 4 ? 8192 : 4096)); gp[i] += 32; }
    }

#pragma unroll
    for (int mi = 0; mi < 8; ++mi)
#pragma unroll
      for (int ni = 0; ni < 4; ++ni)
        acc[mi][ni] = __builtin_amdgcn_mfma_f32_16x16x32_bf16(af[mi], bfr[ni], acc[mi][ni], 0, 0, 0);
    __builtin_amdgcn_sched_barrier(0);       // body stays inside the barrier interval
  }

#pragma unroll
  for (int ni = 0; ni < 4; ++ni) {
    int Cc = nt * 128 + wn * 64 + ni * 16 + r16;
    if (Cc < 64 * d) {
      int g = Cc / d, v = Cc - (Cc / d) * d;
#pragma unroll
      for (int mi = 0; mi < 8; ++mi) {
        int R0 = mt * 256 + wm * 128 + mi * 16 + q * 4;
#pragma unroll
        for (int reg = 0; reg < 4; ++reg) {
          int R = R0 + reg;
          int bb = R / d, m = R - (R / d) * d;
          out[(size_t)bb * XROW + g * 455 + OFF + v * d + m] = acc[mi][ni][reg];
        }
      }
    }
  }
}

__global__ __launch_bounds__(256, 2) void gemm_all(const unsigned short* __restrict__ ws, float* __restrict__ out) {
  __shared__ alignas(16) unsigned short As[3 * 256 * 32];   // 3-deep: 48KB
  __shared__ alignas(16) unsigned short Bs[3 * 128 * 32];   // 3-deep: 24KB (72KB total -> 2 blocks/CU)
  // blocks per l: 2d(d+1) = {4,24,60,112,180,264,364}; cum {4,28,88,200,380,644,1008}
  int b0 = 1007 - (int)blockIdx.x;   // longest-l blocks dispatch first
  if      (b0 <    4) gemm_body<0>(b0,        ws, out, As, Bs);
  else if (b0 <   28) gemm_body<1>(b0 -    4, ws, out, As, Bs);
  else if (b0 <   88) gemm_body<2>(b0 -   28, ws, out, As, Bs);
  else if (b0 <  200) gemm_body<3>(b0 -   88, ws, out, As, Bs);
  else if (b0 <  380) gemm_body<4>(b0 -  200, ws, out, As, Bs);
  else if (b0 <  644) gemm_body<5>(b0 -  380, ws, out, As, Bs);
  else                gemm_body<6>(b0 -  644, ws, out, As, Bs);
}

extern "C" void kernel_launch(void* const* d_in, const int* in_sizes, int n_in,
                              void* d_out, int out_size, void* d_ws, size_t ws_size,
                              hipStream_t stream) {
  const float* x = (const float*)d_in[0];
  const float* D = (const float*)d_in[1];
  const float* w = (const float*)d_in[2];
  float* out = (float*)d_out;
  unsigned short* ws = (unsigned short*)d_ws;   // ~63.8 MB

  hipLaunchKernelGGL(prep, dim3(1472), dim3(256), 0, stream, x, D, w, ws);
  hipLaunchKernelGGL(gemm_all, dim3(1008), dim3(256), 0, stream, ws, out);
}

// Round 8
// 364.527 us; speedup vs baseline: 1.0553x; 1.0553x over previous
//
#include <hip/hip_runtime.h>
#include <stdint.h>

// SO3Conv mapped per l to GEMM: C[(b,m),(g,v)] = A[(b,m),(u,f)] * B[(u,f),(g,v)]
//   A: pre-transposed x, bf16, row-major [M=1024d][K=64d], k = u*64+f
//   B: psi with both norms folded, bf16, B-operand layout Bt[n=(g*d+v)][k], rows padded to 128-mult with 0
// Workspace: A buffers then B buffers, ~63.8 MB.
// R1: double-buffer + XOR swizzle (bank conflicts 5.3M -> 0, dur flat).
// R3/R5: counted-vmcnt 3-buffer pipeline: both 116.5us, MfmaUtil 15%.
// R6: 256x128 tile, wave-tile 128x64: gemm 107.9us. gemm frozen since.
// R7: FAILED prep "vectorization": aligned(4) vector type -> still scalar loads, stride-169 smem
//     added 3.48M bank-conflict cycles; prep 90 -> 129.5us. Reverted approach.
// R8: prep transpose split by f-ROWS ({0,24,44}..{24,44,64}): flat spans start 16B-aligned ->
//     genuine float4 copy with zero index math. smem 43.7KB (Dl chunked to 88 cols in B-build)
//     -> 3 blocks/CU (was 2). Stores uint2, compile-time NQ divisions. gemm identical to R6.

typedef __bf16 bf16x8 __attribute__((ext_vector_type(8)));
typedef float floatx4 __attribute__((ext_vector_type(4)));

#define XROW 29120   // 64*455

__device__ __forceinline__ unsigned short f2bf(float f) {
  union { float f; unsigned int u; } c; c.f = f;
  unsigned int u = c.u;
  return (unsigned short)((u + 0x7FFFu + ((u >> 16) & 1u)) >> 16);
}
__device__ __forceinline__ unsigned int pack2(float a, float b) {
  return (unsigned int)f2bf(a) | ((unsigned int)f2bf(b) << 16);
}

__host__ __device__ constexpr int d_of(int L) { return 2 * L + 1; }
__host__ __device__ constexpr int off_of(int L) { int s = 0; for (int i = 0; i < L; ++i) s += d_of(i) * d_of(i); return s; }
__host__ __device__ constexpr size_t a_off(int L) { size_t s = 0; for (int i = 0; i < L; ++i) s += (size_t)65536 * d_of(i) * d_of(i); return s; }
__host__ __device__ constexpr size_t b_off(int L) { size_t s = a_off(7); for (int i = 0; i < L; ++i) s += (size_t)4096 * d_of(i) * (d_of(i) + 1); return s; }

// Store one f-quad phase of the transpose: quads [Q0, Q0+NQ) (f = 4*quad..), xs holds rows
// f0=4*Q0 .. f0+4*NQ of x (full 455 cols, stride 455).
template <int NQ, int Q0>
__device__ __forceinline__ void store_phase(const float* __restrict__ xs, unsigned short* __restrict__ ws,
                                            int b, int tid) {
  int off = 0; size_t aoff = 0;
#pragma unroll
  for (int l = 0; l < 7; ++l) {
    const int d = 2 * l + 1, d2 = d * d;
    uint2* A2 = (uint2*)(ws + aoff) + (size_t)b * (16 * d2);
    for (int t = tid; t < d2 * NQ; t += 256) {
      int fq = t % NQ, s = t / NQ;           // compile-time NQ -> magic-mul
      int u = s % d, m = s / d;              // compile-time d after unroll
      const float* xc = xs + off + u * d + m;
      uint2 v;
      v.x = pack2(xc[(4 * fq + 0) * 455], xc[(4 * fq + 1) * 455]);
      v.y = pack2(xc[(4 * fq + 2) * 455], xc[(4 * fq + 3) * 455]);
      A2[s * 16 + Q0 + fq] = v;
    }
    off += d2; aoff += (size_t)65536 * d2;
  }
}

// ---------------- Kernel 1 (fused): build B (blocks 0..447) + transpose x (blocks 448..1471) ----------------
__global__ __launch_bounds__(256) void prep(const float* __restrict__ x, const float* __restrict__ Dm,
                                            const float* __restrict__ w, unsigned short* __restrict__ ws) {
  __shared__ __align__(16) float smem[24 * 455];   // 43.7KB: transpose 24 rows; build wg(4352)+Dl(5632)=9984
  const int tid = threadIdx.x;
  const int bid = blockIdx.x;

  if (bid < 448) {
    // ---- build B: psi[f,g,r] = sum_n w[f,g,n] D[n,off+r], norms folded, Dl chunked to 88 cols ----
    float* wg = smem;              // [64][68]: wg[n][f]
    float* Dl = smem + 64 * 68;    // [64][88]: Dl[n][rc], current r-chunk, zero-padded
    const int g = bid & 63, l = bid >> 6;
    const int d = 2 * l + 1, d2 = d * d, K = 64 * d;
    int off = 0; size_t boff = a_off(7);
    for (int i = 0; i < l; ++i) { int dd = 2 * i + 1; off += dd * dd; boff += (size_t)4096 * dd * (dd + 1); }
    unsigned short* B = ws + boff;

    for (int t = tid; t < 4096; t += 256) {
      int n = t & 63, f = t >> 6;
      wg[n * 68 + f] = w[(size_t)f * 4096 + g * 64 + n];
    }

    const float sl = 1.0f / (64.0f * sqrtf((float)d));
    for (int c0 = 0; c0 < d2; c0 += 88) {
      __syncthreads();   // wg ready (1st iter) / Dl free to overwrite (later)
      for (int t = tid; t < 64 * 88; t += 256) {
        int n = t / 88, rc = t - n * 88;
        int r = c0 + rc;
        Dl[t] = (r < d2) ? Dm[n * 455 + off + r] : 0.f;
      }
      __syncthreads();

      const int rem = d2 - c0;
      const int RTc = ((rem > 88 ? 88 : rem) + 3) >> 2;
      for (int tt = tid; tt < 16 * RTc; tt += 256) {
        const int ft = tt & 15, rt = tt >> 4;
        float acc[4][4] = {};
        for (int n = 0; n < 64; ++n) {
          floatx4 wv = *(const floatx4*)(wg + n * 68 + ft * 4);
          floatx4 dv = *(const floatx4*)(Dl + n * 88 + rt * 4);
#pragma unroll
          for (int a = 0; a < 4; ++a)
#pragma unroll
            for (int b2 = 0; b2 < 4; ++b2) acc[a][b2] += wv[a] * dv[b2];
        }
#pragma unroll
        for (int b2 = 0; b2 < 4; ++b2) {
          int r = c0 + rt * 4 + b2;
          if (r < d2) {
            int u = r / d, v = r - u * d;
            size_t base = (size_t)(g * d + v) * K + u * 64 + ft * 4;
#pragma unroll
            for (int a = 0; a < 4; ++a) B[base + a] = f2bf(acc[a][b2] * sl);
          }
        }
      }
    }
    { // zero one pad row per g (rows 64d..64d+63 across the 64 g-blocks)
      int nn = 64 * d + g;
      for (int k = tid; k < K; k += 256) B[(size_t)nn * K + k] = 0;
    }
  } else {
    // ---- transpose x -> A (bf16): f-row phases {0..24, 24..44, 44..64}; flat float4 copy ----
    float* xs = smem;
    const int b = bid - 448;
    const float* xb = x + (size_t)b * XROW;

    // phase A: rows 0..24 (span start 0 mod 4 = 0: aligned)
    {
      const floatx4* src = (const floatx4*)xb;
      floatx4* dst = (floatx4*)xs;
      for (int t = tid; t < 24 * 455 / 4; t += 256) dst[t] = src[t];
    }
    __syncthreads();
    store_phase<6, 0>(xs, ws, b, tid);
    __syncthreads();
    // phase B: rows 24..44 (24*455=10920, mod 4 = 0: aligned)
    {
      const floatx4* src = (const floatx4*)(xb + 24 * 455);
      floatx4* dst = (floatx4*)xs;
      for (int t = tid; t < 20 * 455 / 4; t += 256) dst[t] = src[t];
    }
    __syncthreads();
    store_phase<5, 6>(xs, ws, b, tid);
    __syncthreads();
    // phase C: rows 44..64 (44*455=20020, mod 4 = 0: aligned)
    {
      const floatx4* src = (const floatx4*)(xb + 44 * 455);
      floatx4* dst = (floatx4*)xs;
      for (int t = tid; t < 20 * 455 / 4; t += 256) dst[t] = src[t];
    }
    __syncthreads();
    store_phase<5, 11>(xs, ws, b, tid);
  }
}

// ---------------- Kernel 2: fused all-l MFMA GEMM, 256x128 tile, wave-tile 128x64 (8x4 frags) ----------------
__device__ __forceinline__ void async_copy16(const void* gp, void* lp) {
  __builtin_amdgcn_global_load_lds((__attribute__((address_space(1))) void*)gp,
                                   (__attribute__((address_space(3))) void*)lp, 16, 0, 0);
}

template <int N>
__device__ __forceinline__ void wait_vmcnt() {
  asm volatile("s_waitcnt vmcnt(%0)" :: "n"(N) : "memory");
}

template <int L>
__device__ __forceinline__ void gemm_body(int local, const unsigned short* __restrict__ ws,
                                          float* __restrict__ out,
                                          unsigned short* As, unsigned short* Bs) {
  constexpr int d = 2 * L + 1;
  constexpr int K = 64 * d;
  constexpr int NT = (d + 1) / 2;          // N-tiles of 128 (N padded to 64*(d+1)); M-tiles of 256 = 4d
  constexpr int OFF = off_of(L);
  constexpr int KT = 2 * d;                // 32-wide k-steps
  const unsigned short* A = ws + a_off(L);
  const unsigned short* B = ws + b_off(L);
  // XCD-grouped dispatch: groups of 4 consecutive bids share the B-panel nt across 4 M-tiles.
  const int x4 = local & 3, tt = local >> 2;
  const int mt = (tt / NT) * 4 + x4;
  const int nt = tt % NT;
  const int tid = threadIdx.x;
  const int w = tid >> 6, ln = tid & 63;
  const int wm = w >> 1, wn = w & 1;       // wave-tile: rows wm*128..+128, cols wn*64..+64
  const int q = ln >> 4, r16 = ln & 15;

  // Staging: LDS dest linear (global_load_lds requirement); bank-conflict swizzle applied by
  // permuting the 16B k-chunk in the GLOBAL source address: chunk ^= (row>>1)&3.
  const unsigned short* gp[6];
  unsigned short* ldst[6];
#pragma unroll
  for (int i = 0; i < 6; ++i) {
    int c = i * 256 + tid;
    if (i < 4) {
      int row = c >> 2, ch = (c & 3) ^ ((c >> 3) & 3);
      gp[i] = A + (size_t)(mt * 256 + row) * K + ch * 8;
      ldst[i] = As + (i * 256 + w * 64) * 8;
    } else {
      int c2 = c - 1024;
      int row = c2 >> 2, ch = (c2 & 3) ^ ((c2 >> 3) & 3);
      gp[i] = B + (size_t)(nt * 128 + row) * K + ch * 8;
      ldst[i] = Bs + ((i - 4) * 256 + w * 64) * 8;
    }
  }

  // ds_read offsets with the matching XOR: stored chunk at slot (q^s) is global chunk q, s=(row>>1)&3
  const int sq = q ^ ((r16 >> 1) & 3);
  const int aoffs0 = (wm * 128 + r16) * 32 + sq * 8;   // af[mi] at +mi*512 (16 rows)
  const int boffs0 = (wn * 64 + r16) * 32 + sq * 8;    // bfr[ni] at +ni*512

  floatx4 acc[8][4] = {};

  // prologue: stage tiles 0,1 (6 global_load_lds each)
#pragma unroll
  for (int t = 0; t < 2; ++t) {
    if (t < KT) {
#pragma unroll
      for (int i = 0; i < 6; ++i) { async_copy16(gp[i], ldst[i] + t * (i < 4 ? 8192 : 4096)); gp[i] += 32; }
    }
  }

#pragma unroll
  for (int kt = 0; kt < KT; ++kt) {
    // Wait for tile kt: at most 1 younger tile (6 loads) in flight. Never 0 in steady state.
    if (kt < KT - 1) wait_vmcnt<6>();
    else             wait_vmcnt<0>();
    __builtin_amdgcn_s_barrier();            // tile kt resident for ALL waves
    __builtin_amdgcn_sched_barrier(0);       // nothing below may hoist above the rendezvous

    const unsigned short* Asc = As + (kt % 3) * 8192;
    const unsigned short* Bsc = Bs + (kt % 3) * 4096;
    bf16x8 af[8], bfr[4];
#pragma unroll
    for (int mi = 0; mi < 8; ++mi) af[mi] = *(const bf16x8*)(Asc + aoffs0 + mi * 512);
#pragma unroll
    for (int ni = 0; ni < 4; ++ni) bfr[ni] = *(const bf16x8*)(Bsc + boffs0 + ni * 512);

    if (kt + 2 < KT) {
      // buffer (kt+2)%3 == (kt-1)%3: safe — all waves past barrier kt have issued their kt-1 MFMAs,
      // whose compiler-inserted lgkmcnt waits retired the kt-1 ds_reads.
#pragma unroll
      for (int i = 0; i < 6; ++i) { async_copy16(gp[i], ldst[i] + ((kt + 2) % 3) * (i < 4 ? 8192 : 4096)); gp[i] += 32; }
    }

#pragma unroll
    for (int mi = 0; mi < 8; ++mi)
#pragma unroll
      for (int ni = 0; ni < 4; ++ni)
        acc[mi][ni] = __builtin_amdgcn_mfma_f32_16x16x32_bf16(af[mi], bfr[ni], acc[mi][ni], 0, 0, 0);
    __builtin_amdgcn_sched_barrier(0);       // body stays inside the barrier interval
  }

#pragma unroll
  for (int ni = 0; ni < 4; ++ni) {
    int Cc = nt * 128 + wn * 64 + ni * 16 + r16;
    if (Cc < 64 * d) {
      int g = Cc / d, v = Cc - (Cc / d) * d;
#pragma unroll
      for (int mi = 0; mi < 8; ++mi) {
        int R0 = mt * 256 + wm * 128 + mi * 16 + q * 4;
#pragma unroll
        for (int reg = 0; reg < 4; ++reg) {
          int R = R0 + reg;
          int bb = R / d, m = R - (R / d) * d;
          out[(size_t)bb * XROW + g * 455 + OFF + v * d + m] = acc[mi][ni][reg];
        }
      }
    }
  }
}

__global__ __launch_bounds__(256, 2) void gemm_all(const unsigned short* __restrict__ ws, float* __restrict__ out) {
  __shared__ alignas(16) unsigned short As[3 * 256 * 32];   // 3-deep: 48KB
  __shared__ alignas(16) unsigned short Bs[3 * 128 * 32];   // 3-deep: 24KB (72KB total -> 2 blocks/CU)
  // blocks per l: 2d(d+1) = {4,24,60,112,180,264,364}; cum {4,28,88,200,380,644,1008}
  int b0 = 1007 - (int)blockIdx.x;   // longest-l blocks dispatch first
  if      (b0 <    4) gemm_body<0>(b0,        ws, out, As, Bs);
  else if (b0 <   28) gemm_body<1>(b0 -    4, ws, out, As, Bs);
  else if (b0 <   88) gemm_body<2>(b0 -   28, ws, out, As, Bs);
  else if (b0 <  200) gemm_body<3>(b0 -   88, ws, out, As, Bs);
  else if (b0 <  380) gemm_body<4>(b0 -  200, ws, out, As, Bs);
  else if (b0 <  644) gemm_body<5>(b0 -  380, ws, out, As, Bs);
  else                gemm_body<6>(b0 -  644, ws, out, As, Bs);
}

extern "C" void kernel_launch(void* const* d_in, const int* in_sizes, int n_in,
                              void* d_out, int out_size, void* d_ws, size_t ws_size,
                              hipStream_t stream) {
  const float* x = (const float*)d_in[0];
  const float* D = (const float*)d_in[1];
  const float* w = (const float*)d_in[2];
  float* out = (float*)d_out;
  unsigned short* ws = (unsigned short*)d_ws;   // ~63.8 MB

  hipLaunchKernelGGL(prep, dim3(1472), dim3(256), 0, stream, x, D, w, ws);
  hipLaunchKernelGGL(gemm_all, dim3(1008), dim3(256), 0, stream, ws, out);
}

// Round 9
// 336.878 us; speedup vs baseline: 1.1419x; 1.0821x over previous
//
#include <hip/hip_runtime.h>
#include <stdint.h>

// SO3Conv mapped per l to GEMM: C[(b,m),(g,v)] = A[(b,m),(u,f)] * B[(u,f),(g,v)]
//   A: pre-transposed x, bf16, row-major [M=1024d][K=64d], k = u*64+f
//   B: psi with both norms folded, bf16, B-operand layout Bt[n=(g*d+v)][k], rows padded to 128-mult with 0
// Workspace: A buffers then B buffers, ~63.8 MB.
// R1: double-buffer + XOR swizzle (bank conflicts 5.3M -> 0, dur flat).
// R3/R5: counted-vmcnt 3-buffer pipeline: both 116.5us, MfmaUtil 15%.
// R6: gemm 256x128 tile, wave-tile 128x64: 107.9us. gemm frozen since (best).
// R7: FAILED prep col-split "vectorization" (aligned(4) type -> scalar loads + stride-169 conflicts).
// R8: FAILED prep f-row-split (real float4 loads BUT partial-128B-line A-stores: WRITE 62->95MB).
// R9: prep = R0's verified transpose (coalesced loads+stores, 89us @ 2 blk/CU) + R8's verified
//     Dl-chunked build; smem 60KB -> 43.3KB => 3 blocks/CU. Same access patterns, +50% occupancy.

typedef __bf16 bf16x8 __attribute__((ext_vector_type(8)));
typedef float floatx4 __attribute__((ext_vector_type(4)));

#define XROW 29120   // 64*455

__device__ __forceinline__ unsigned short f2bf(float f) {
  union { float f; unsigned int u; } c; c.f = f;
  unsigned int u = c.u;
  return (unsigned short)((u + 0x7FFFu + ((u >> 16) & 1u)) >> 16);
}
__device__ __forceinline__ unsigned int pack2(float a, float b) {
  return (unsigned int)f2bf(a) | ((unsigned int)f2bf(b) << 16);
}

__host__ __device__ constexpr int d_of(int L) { return 2 * L + 1; }
__host__ __device__ constexpr int off_of(int L) { int s = 0; for (int i = 0; i < L; ++i) s += d_of(i) * d_of(i); return s; }
__host__ __device__ constexpr size_t a_off(int L) { size_t s = 0; for (int i = 0; i < L; ++i) s += (size_t)65536 * d_of(i) * d_of(i); return s; }
__host__ __device__ constexpr size_t b_off(int L) { size_t s = a_off(7); for (int i = 0; i < L; ++i) s += (size_t)4096 * d_of(i) * (d_of(i) + 1); return s; }

// ---------------- Kernel 1 (fused): build B (blocks 0..447) + transpose x (blocks 448..1471) ----------------
__global__ __launch_bounds__(256) void prep(const float* __restrict__ x, const float* __restrict__ Dm,
                                            const float* __restrict__ w, unsigned short* __restrict__ ws) {
  __shared__ __align__(16) float smem[64 * 169];   // 43.3KB -> 3 blocks/CU. build: 9984; transpose: <=10816
  const int tid = threadIdx.x;
  const int bid = blockIdx.x;

  if (bid < 448) {
    // ---- build B: psi[f,g,r] = sum_n w[f,g,n] D[n,off+r], norms folded, Dl chunked to 88 cols ----
    float* wg = smem;              // [64][68]: wg[n][f]
    float* Dl = smem + 64 * 68;    // [64][88]: Dl[n][rc], current r-chunk, zero-padded
    const int g = bid & 63, l = bid >> 6;
    const int d = 2 * l + 1, d2 = d * d, K = 64 * d;
    int off = 0; size_t boff = a_off(7);
    for (int i = 0; i < l; ++i) { int dd = 2 * i + 1; off += dd * dd; boff += (size_t)4096 * dd * (dd + 1); }
    unsigned short* B = ws + boff;

    for (int t = tid; t < 4096; t += 256) {
      int n = t & 63, f = t >> 6;
      wg[n * 68 + f] = w[(size_t)f * 4096 + g * 64 + n];
    }

    const float sl = 1.0f / (64.0f * sqrtf((float)d));
    for (int c0 = 0; c0 < d2; c0 += 88) {
      __syncthreads();   // wg ready (1st iter) / Dl free to overwrite (later)
      for (int t = tid; t < 64 * 88; t += 256) {
        int n = t / 88, rc = t - n * 88;
        int r = c0 + rc;
        Dl[t] = (r < d2) ? Dm[n * 455 + off + r] : 0.f;
      }
      __syncthreads();

      const int rem = d2 - c0;
      const int RTc = ((rem > 88 ? 88 : rem) + 3) >> 2;
      for (int tt = tid; tt < 16 * RTc; tt += 256) {
        const int ft = tt & 15, rt = tt >> 4;
        float acc[4][4] = {};
        for (int n = 0; n < 64; ++n) {
          floatx4 wv = *(const floatx4*)(wg + n * 68 + ft * 4);
          floatx4 dv = *(const floatx4*)(Dl + n * 88 + rt * 4);
#pragma unroll
          for (int a = 0; a < 4; ++a)
#pragma unroll
            for (int b2 = 0; b2 < 4; ++b2) acc[a][b2] += wv[a] * dv[b2];
        }
#pragma unroll
        for (int b2 = 0; b2 < 4; ++b2) {
          int r = c0 + rt * 4 + b2;
          if (r < d2) {
            int u = r / d, v = r - u * d;
            size_t base = (size_t)(g * d + v) * K + u * 64 + ft * 4;
#pragma unroll
            for (int a = 0; a < 4; ++a) B[base + a] = f2bf(acc[a][b2] * sl);
          }
        }
      }
    }
    { // zero one pad row per g (rows 64d..64d+63 across the 64 g-blocks)
      int nn = 64 * d + g;
      for (int k = tid; k < K; k += 256) B[(size_t)nn * K + k] = 0;
    }
  } else {
    // ---- transpose x -> A (bf16, pair-packed 4B coalesced stores) — R0 verified structure ----
    float* xs = smem;
    const int b = bid - 448;
    const float* xb = x + (size_t)b * XROW;
    size_t aoff = 0;

    // phase A: l0..l4 (cols 0..165)
    for (int t = tid; t < 64 * 165; t += 256) { int f = t / 165, c = t - f * 165; xs[t] = xb[(size_t)f * 455 + c]; }
    __syncthreads();
    int off = 0;
#pragma unroll
    for (int l = 0; l < 5; ++l) {
      const int d = 2 * l + 1, d2 = d * d, n1 = 64 * d2;
      unsigned int* A = (unsigned int*)(ws + aoff + (size_t)b * n1);
      for (int t = tid; t < (n1 >> 1); t += 256) {
        int f2 = t & 31, s = t >> 5;
        int u = s % d, m = s / d;
        int c = off + u * d + m;
        A[t] = pack2(xs[(2 * f2) * 165 + c], xs[(2 * f2 + 1) * 165 + c]);
      }
      off += d2; aoff += (size_t)1024 * n1;
    }
    __syncthreads();
    // phase B: l5 (cols 165..286)
    for (int t = tid; t < 64 * 121; t += 256) { int f = t / 121, c = t - f * 121; xs[t] = xb[(size_t)f * 455 + 165 + c]; }
    __syncthreads();
    {
      const int n1 = 64 * 121;
      unsigned int* A = (unsigned int*)(ws + aoff + (size_t)b * n1);
      for (int t = tid; t < (n1 >> 1); t += 256) {
        int f2 = t & 31, s = t >> 5;
        int u = s % 11, m = s / 11;
        int c = u * 11 + m;
        A[t] = pack2(xs[(2 * f2) * 121 + c], xs[(2 * f2 + 1) * 121 + c]);
      }
      aoff += (size_t)1024 * n1;
    }
    __syncthreads();
    // phase C: l6 (cols 286..455)
    for (int t = tid; t < 64 * 169; t += 256) { int f = t / 169, c = t - f * 169; xs[t] = xb[(size_t)f * 455 + 286 + c]; }
    __syncthreads();
    {
      const int n1 = 64 * 169;
      unsigned int* A = (unsigned int*)(ws + aoff + (size_t)b * n1);
      for (int t = tid; t < (n1 >> 1); t += 256) {
        int f2 = t & 31, s = t >> 5;
        int u = s % 13, m = s / 13;
        int c = u * 13 + m;
        A[t] = pack2(xs[(2 * f2) * 169 + c], xs[(2 * f2 + 1) * 169 + c]);
      }
    }
  }
}

// ---------------- Kernel 2: fused all-l MFMA GEMM, 256x128 tile, wave-tile 128x64 (8x4 frags) ----------------
__device__ __forceinline__ void async_copy16(const void* gp, void* lp) {
  __builtin_amdgcn_global_load_lds((__attribute__((address_space(1))) void*)gp,
                                   (__attribute__((address_space(3))) void*)lp, 16, 0, 0);
}

template <int N>
__device__ __forceinline__ void wait_vmcnt() {
  asm volatile("s_waitcnt vmcnt(%0)" :: "n"(N) : "memory");
}

template <int L>
__device__ __forceinline__ void gemm_body(int local, const unsigned short* __restrict__ ws,
                                          float* __restrict__ out,
                                          unsigned short* As, unsigned short* Bs) {
  constexpr int d = 2 * L + 1;
  constexpr int K = 64 * d;
  constexpr int NT = (d + 1) / 2;          // N-tiles of 128 (N padded to 64*(d+1)); M-tiles of 256 = 4d
  constexpr int OFF = off_of(L);
  constexpr int KT = 2 * d;                // 32-wide k-steps
  const unsigned short* A = ws + a_off(L);
  const unsigned short* B = ws + b_off(L);
  // XCD-grouped dispatch: groups of 4 consecutive bids share the B-panel nt across 4 M-tiles.
  const int x4 = local & 3, tt = local >> 2;
  const int mt = (tt / NT) * 4 + x4;
  const int nt = tt % NT;
  const int tid = threadIdx.x;
  const int w = tid >> 6, ln = tid & 63;
  const int wm = w >> 1, wn = w & 1;       // wave-tile: rows wm*128..+128, cols wn*64..+64
  const int q = ln >> 4, r16 = ln & 15;

  // Staging: LDS dest linear (global_load_lds requirement); bank-conflict swizzle applied by
  // permuting the 16B k-chunk in the GLOBAL source address: chunk ^= (row>>1)&3.
  const unsigned short* gp[6];
  unsigned short* ldst[6];
#pragma unroll
  for (int i = 0; i < 6; ++i) {
    int c = i * 256 + tid;
    if (i < 4) {
      int row = c >> 2, ch = (c & 3) ^ ((c >> 3) & 3);
      gp[i] = A + (size_t)(mt * 256 + row) * K + ch * 8;
      ldst[i] = As + (i * 256 + w * 64) * 8;
    } else {
      int c2 = c - 1024;
      int row = c2 >> 2, ch = (c2 & 3) ^ ((c2 >> 3) & 3);
      gp[i] = B + (size_t)(nt * 128 + row) * K + ch * 8;
      ldst[i] = Bs + ((i - 4) * 256 + w * 64) * 8;
    }
  }

  // ds_read offsets with the matching XOR: stored chunk at slot (q^s) is global chunk q, s=(row>>1)&3
  const int sq = q ^ ((r16 >> 1) & 3);
  const int aoffs0 = (wm * 128 + r16) * 32 + sq * 8;   // af[mi] at +mi*512 (16 rows)
  const int boffs0 = (wn * 64 + r16) * 32 + sq * 8;    // bfr[ni] at +ni*512

  floatx4 acc[8][4] = {};

  // prologue: stage tiles 0,1 (6 global_load_lds each)
#pragma unroll
  for (int t = 0; t < 2; ++t) {
    if (t < KT) {
#pragma unroll
      for (int i = 0; i < 6; ++i) { async_copy16(gp[i], ldst[i] + t * (i < 4 ? 8192 : 4096)); gp[i] += 32; }
    }
  }

#pragma unroll
  for (int kt = 0; kt < KT; ++kt) {
    // Wait for tile kt: at most 1 younger tile (6 loads) in flight. Never 0 in steady state.
    if (kt < KT - 1) wait_vmcnt<6>();
    else             wait_vmcnt<0>();
    __builtin_amdgcn_s_barrier();            // tile kt resident for ALL waves
    __builtin_amdgcn_sched_barrier(0);       // nothing below may hoist above the rendezvous

    const unsigned short* Asc = As + (kt % 3) * 8192;
    const unsigned short* Bsc = Bs + (kt % 3) * 4096;
    bf16x8 af[8], bfr[4];
#pragma unroll
    for (int mi = 0; mi < 8; ++mi) af[mi] = *(const bf16x8*)(Asc + aoffs0 + mi * 512);
#pragma unroll
    for (int ni = 0; ni < 4; ++ni) bfr[ni] = *(const bf16x8*)(Bsc + boffs0 + ni * 512);

    if (kt + 2 < KT) {
      // buffer (kt+2)%3 == (kt-1)%3: safe — all waves past barrier kt have issued their kt-1 MFMAs,
      // whose compiler-inserted lgkmcnt waits retired the kt-1 ds_reads.
#pragma unroll
      for (int i = 0; i < 6; ++i) { async_copy16(gp[i], ldst[i] + ((kt + 2) % 3) * (i < 4 ? 8192 : 4096)); gp[i] += 32; }
    }

#pragma unroll
    for (int mi = 0; mi < 8; ++mi)
#pragma unroll
      for (int ni = 0; ni < 4; ++ni)
        acc[mi][ni] = __builtin_amdgcn_mfma_f32_16x16x32_bf16(af[mi], bfr[ni], acc[mi][ni], 0, 0, 0);
    __builtin_amdgcn_sched_barrier(0);       // body stays inside the barrier interval
  }

#pragma unroll
  for (int ni = 0; ni < 4; ++ni) {
    int Cc = nt * 128 + wn * 64 + ni * 16 + r16;
    if (Cc < 64 * d) {
      int g = Cc / d, v = Cc - (Cc / d) * d;
#pragma unroll
      for (int mi = 0; mi < 8; ++mi) {
        int R0 = mt * 256 + wm * 128 + mi * 16 + q * 4;
#pragma unroll
        for (int reg = 0; reg < 4; ++reg) {
          int R = R0 + reg;
          int bb = R / d, m = R - (R / d) * d;
          out[(size_t)bb * XROW + g * 455 + OFF + v * d + m] = acc[mi][ni][reg];
        }
      }
    }
  }
}

__global__ __launch_bounds__(256, 2) void gemm_all(const unsigned short* __restrict__ ws, float* __restrict__ out) {
  __shared__ alignas(16) unsigned short As[3 * 256 * 32];   // 3-deep: 48KB
  __shared__ alignas(16) unsigned short Bs[3 * 128 * 32];   // 3-deep: 24KB (72KB total -> 2 blocks/CU)
  // blocks per l: 2d(d+1) = {4,24,60,112,180,264,364}; cum {4,28,88,200,380,644,1008}
  int b0 = 1007 - (int)blockIdx.x;   // longest-l blocks dispatch first
  if      (b0 <    4) gemm_body<0>(b0,        ws, out, As, Bs);
  else if (b0 <   28) gemm_body<1>(b0 -    4, ws, out, As, Bs);
  else if (b0 <   88) gemm_body<2>(b0 -   28, ws, out, As, Bs);
  else if (b0 <  200) gemm_body<3>(b0 -   88, ws, out, As, Bs);
  else if (b0 <  380) gemm_body<4>(b0 -  200, ws, out, As, Bs);
  else if (b0 <  644) gemm_body<5>(b0 -  380, ws, out, As, Bs);
  else                gemm_body<6>(b0 -  644, ws, out, As, Bs);
}

extern "C" void kernel_launch(void* const* d_in, const int* in_sizes, int n_in,
                              void* d_out, int out_size, void* d_ws, size_t ws_size,
                              hipStream_t stream) {
  const float* x = (const float*)d_in[0];
  const float* D = (const float*)d_in[1];
  const float* w = (const float*)d_in[2];
  float* out = (float*)d_out;
  unsigned short* ws = (unsigned short*)d_ws;   // ~63.8 MB

  hipLaunchKernelGGL(prep, dim3(1472), dim3(256), 0, stream, x, D, w, ws);
  hipLaunchKernelGGL(gemm_all, dim3(1008), dim3(256), 0, stream, ws, out);
}